// Round 7
// baseline (47.132 us; speedup 1.0000x reference)
//
#include <hip/hip_runtime.h>

#define FRAME 160
#define ORDER 16
#define LPC_EPS 1e-8f
#define NF 32        // frames per tile
#define BS 256       // 4 waves; 8 threads per frame
#define SEG 20       // samples per part (8 parts per frame)
#define SXF 164      // floats per frame row (41 quads: 40 real + 1 pad) = skew
#define WCH 1536     // floats per wave chunk (384 quads: 328 used + 56 pad)
#define TQ (NF * FRAME)  // 5120 floats per tile
#define T 2          // tiles per block, double-buffered DMA pipeline

// Round 7: T3/T4 async pipeline via global_load_lds + RAW s_barrier + counted
// vmcnt. Ledger: dur pinned ~40us across VALU 27%..50% (r0/r1/r6) => bound by
// SERIALIZED memory phases, not VALU/barriers. r5's register prefetch was
// defeated by hipcc's vmcnt(0)-drain before __syncthreads + scratch spills.
// global_load_lds has no data VGPRs (nothing to spill) and raw s_barrier is
// NOT auto-drained (m201-verified mechanism): tile t+1's DMA flies across the
// barrier and the whole compute phase, drained by vmcnt(11)/(5) at tile top.
// Wave-privacy makes counted per-wave vmcnt sufficient: each wave DMAs its
// own 8 frames into its own 1536-float chunk (41-quad skewed rows preserved
// => compute addressing and bank behavior identical to the 39.75us r1), FIRs
// in place, and stores its own chunk out (1024B/instr coalesced). The one
// raw barrier per tile only clusters traffic (r4: de-clustering costs +13us).
__device__ __forceinline__ void dma16(const float* g, float* l) {
    __builtin_amdgcn_global_load_lds(
        (const __attribute__((address_space(1))) void*)g,
        (__attribute__((address_space(3))) void*)l, 16, 0, 0);
}

__global__ __launch_bounds__(BS, 4) void lpc_fused(const float* __restrict__ x,
                                                   float* __restrict__ out) {
    __shared__ float xs[2][4 * WCH];  // 2 x 24,576 B = 49,152 B -> 3 blocks/CU

    const int t = threadIdx.x;
    const int wv = t >> 6;       // wave id [0,4)
    const int ln = t & 63;       // lane
    const long long tile0 = (long long)blockIdx.x * T;

    const int fi = t >> 3;       // frame within tile [0,32); fi>>3 == wv
    const int part = t & 7;      // n-range: [20*part, 20*part+20)
    const int sbase = SEG * part;
    const int rowb = wv * WCH + (fi & 7) * SXF;  // this group's frame row

    // ---- DMA issue: 6 full-wave rounds, uniform LDS dest per round ----
    // round it writes LDS [wv*WCH + it*256 .. +256) floats (lane*16B slots);
    // lane ln sources global quad for chunk-quad ql = it*64+ln:
    // frame fl = ql/41, off = ql%41; pads (off==40 or fl>=8) read a dummy
    // in-tile address and land in never-read LDS pad words.
    auto issue = [&](int c, long long gbase) {
#pragma unroll
        for (int it = 0; it < 6; ++it) {
            int ql = it * 64 + ln;                  // [0,384)
            int fl = ql / 41;                       // 0..9
            int off = ql - fl * 41;                 // 0..40
            int rf = (fl < 8) ? fl : 7;
            int ro = (off < 40) ? off : 39;
            int gq = (wv * 8 + rf) * 40 + ro;       // real quad in tile
            dma16(x + gbase + (long long)gq * 4,
                  &xs[c][wv * WCH + it * 256]);     // uniform base; HW adds lane*16
        }
    };

    issue(0, tile0 * TQ);  // prologue: tile 0 -> buf 0 (6 DMA in flight)

#pragma unroll
    for (int tt = 0; tt < T; ++tt) {
        const int c = tt & 1;
        const long long gbase = (tile0 + tt) * TQ;

        if (tt + 1 < T) issue(c ^ 1, gbase + TQ);   // next tile's DMA: in flight
                                                    // across barrier + compute
        // drain OUR buf-c DMAs only (counted; never vmcnt(0) mid-pipeline):
        // outstanding = [bufc 6][stores_prev 5][next 6]; keep the newer ones.
        if (tt == 0)            asm volatile("s_waitcnt vmcnt(6)" ::: "memory");
        else if (tt + 1 < T)    asm volatile("s_waitcnt vmcnt(11)" ::: "memory");
        else                    asm volatile("s_waitcnt vmcnt(5)" ::: "memory");
        __builtin_amdgcn_sched_barrier(0);
        __builtin_amdgcn_s_barrier();   // clustering only (all state wave-private)

        // ---- window w[j] = x[sbase+j], j in [0,36), zero-padded past end ----
        float w[SEG + ORDER];
#pragma unroll
        for (int m = 0; m < (SEG + ORDER) / 4; ++m) {
            int idx = sbase + 4 * m;
            float4 v = make_float4(0.f, 0.f, 0.f, 0.f);
            if (idx < FRAME) v = *(const float4*)(&xs[c][rowb + idx]);
            w[4 * m + 0] = v.x; w[4 * m + 1] = v.y;
            w[4 * m + 2] = v.z; w[4 * m + 3] = v.w;
        }

        // ---- FIR look-back: pre[j] = x[sbase-16+j], zeros before start ----
        float pre[ORDER];
#pragma unroll
        for (int m = 0; m < ORDER / 4; ++m) {
            int idx = sbase - ORDER + 4 * m;
            float4 v = make_float4(0.f, 0.f, 0.f, 0.f);
            if (idx >= 0) v = *(const float4*)(&xs[c][rowb + idx]);
            pre[4 * m + 0] = v.x; pre[4 * m + 1] = v.y;
            pre[4 * m + 2] = v.z; pre[4 * m + 3] = v.w;
        }

        // ---- partial autocorrelation over 20 samples, all 17 lags ----
        float r[ORDER + 1];
#pragma unroll
        for (int k = 0; k <= ORDER; ++k) r[k] = 0.f;
#pragma unroll
        for (int n = 0; n < SEG; ++n) {
#pragma unroll
            for (int k = 0; k <= ORDER; ++k) {
                r[k] = fmaf(w[n], w[n + k], r[k]);
            }
        }
        // 8-lane butterfly: every lane of the group gets full-frame r[k]
#pragma unroll
        for (int k = 0; k <= ORDER; ++k) {
            r[k] += __shfl_xor(r[k], 1);
            r[k] += __shfl_xor(r[k], 2);
            r[k] += __shfl_xor(r[k], 4);
        }

        // ---- gather: lane L adopts frame (L&7); source lane (L&7)*8 ----
        float rr[ORDER + 1];
#pragma unroll
        for (int k = 0; k <= ORDER; ++k)
            rr[k] = __shfl(r[k], (ln & 7) << 3);

        // ---- Levinson-Durbin (all waves in parallel, 8x lane-redundant) ----
        float ao[ORDER + 1];
        ao[0] = 1.f;
#pragma unroll
        for (int j = 1; j <= ORDER; ++j) ao[j] = 0.f;
        float e = (rr[0] != 0.f) ? rr[0] : LPC_EPS;
#pragma unroll
        for (int i = 1; i <= ORDER; ++i) {
            float acc = rr[i];
#pragma unroll
            for (int j = 1; j < i; ++j) acc -= ao[j] * rr[i - j];
            float k = acc * __builtin_amdgcn_rcpf(e);  // e >= EPS > 0 always
#pragma unroll
            for (int j = 1; 2 * j < i; ++j) {
                float aj = ao[j], aij = ao[i - j];
                ao[j]     = aj  - k * aij;
                ao[i - j] = aij - k * aj;
            }
            if ((i & 1) == 0) {
                int m = i >> 1;
                ao[m] = ao[m] - k * ao[m];
            }
            ao[i] = k;
            e = fmaxf(e * (1.f - k * k), LPC_EPS);
        }

        // ---- scatter: lane ln takes a[] of its own frame (ln>>3) ----
        float a[ORDER + 1];
        a[0] = 1.f;
#pragma unroll
        for (int k = 1; k <= ORDER; ++k)
            a[k] = __shfl(ao[k], ln >> 3);

        // ---- FIR in place (this wave's rows only; w/pre already in regs) ----
#pragma unroll
        for (int m = 0; m < SEG / 4; ++m) {
            float o[4];
#pragma unroll
            for (int i = 0; i < 4; ++i) {
                int n = 4 * m + i;
                float s = 0.f;
#pragma unroll
                for (int k = 0; k <= ORDER; ++k) {
                    int j = n - k;                       // compile-time
                    float xv = (j >= 0) ? w[j] : pre[ORDER + j];
                    s = fmaf(a[k], xv, s);
                }
                o[i] = s;
            }
            *(float4*)(&xs[c][rowb + sbase + 4 * m]) =
                make_float4(o[0], o[1], o[2], o[3]);
        }
        // our FIR ds_writes must land before our stage-out ds_reads
        asm volatile("s_waitcnt lgkmcnt(0)" ::: "memory");
        __builtin_amdgcn_sched_barrier(0);

        // ---- stage out: wave-private, 5 x 1024B-contiguous stores ----
#pragma unroll
        for (int it = 0; it < 5; ++it) {
            int ql = it * 64 + ln;                  // real quad in chunk [0,320)
            int fl = ql / 40;
            int off4 = (ql - fl * 40) * 4;
            float4 v = *(const float4*)(&xs[c][wv * WCH + fl * SXF + off4]);
            *(float4*)(out + gbase + (long long)(wv * 320 + ql) * 4) = v;
        }
        // next iteration's DMA into buf c^1 is already flying; the DMA that
        // reuses buf c is issued only after these reads completed (program
        // order + lgkmcnt before stores' data use) -- wave-private, safe.
    }
}

extern "C" void kernel_launch(void* const* d_in, const int* in_sizes, int n_in,
                              void* d_out, int out_size, void* d_ws, size_t ws_size,
                              hipStream_t stream) {
    const float* x = (const float*)d_in[0];
    float* out = (float*)d_out;
    int total = in_sizes[0];                 // 20,480,000 = 128,000 frames
    int n_frames = total / FRAME;
    int n_blocks = n_frames / NF / T;        // 2000 (exact for this shape)
    lpc_fused<<<n_blocks, BS, 0, stream>>>(x, out);
}

// Round 9
// 38.560 us; speedup vs baseline: 1.2223x; 1.2223x over previous
//
#include <hip/hip_runtime.h>

#define FRAME 160
#define ORDER 16
#define LPC_EPS 1e-8f
#define NF 32        // frames per block
#define BS 256       // threads per block (4 waves); 8 threads per frame
#define SEG 20       // samples per part (8 parts per frame)
#define SX 164       // padded LDS row stride in floats (+4-float skew vs 160)
#define AB 20        // rbuf/abuf row stride in floats
#define QPB (NF * FRAME / 4 / BS)  // 5 float4 iterations per thread stage-in/out

// Native clang vector for nontemporal builtin (HIP_vector_type is a class ->
// rejected by __builtin_nontemporal_store; ext_vector_type is accepted and
// lowers to the same global_store_dwordx4, with the nt policy bit set).
typedef float f4nt __attribute__((ext_vector_type(4)));

// Round 9 = round-1 skeleton (the 39.75us best) + NON-TEMPORAL stage-out.
// Ledger: dur pinned ~40us across VALU 27..50%, 2..4 barriers (r0/r1/r6);
// every memory-de-clustering change lost big (r4 zero-barrier: FETCH 44->64MB
// +13us; r5 reg-prefetch: WRITE 95->150MB +13us; r7 DMA dbuf: occupancy
// 37->29% +7us). Binding resource = effective HBM/L3 bandwidth. r1 steady
// state fetches 40MB/dispatch -- half the 82MB input misses L3 because the
// 82MB output WRITE stream (write-allocate) evicts it between iterations.
// The kernel never re-reads its output: store it nt (bypass L2/L3 retention)
// so the input stays L3-resident -> FETCH toward ~0, HBM approaches the 80MB
// compulsory write floor (~13us). Everything else byte-identical to r1.
__global__ __launch_bounds__(BS, 4) void lpc_fused(const float* __restrict__ x,
                                                   float* __restrict__ out) {
    __shared__ float xs[NF * SX];    // 20,992 B
    __shared__ float rbuf[NF * AB];  //  2,560 B
    __shared__ float abuf[NF * AB];  //  2,560 B

    const int t = threadIdx.x;
    const long long base = (long long)blockIdx.x * (NF * FRAME);

    // ---- stage in: 1280 consecutive float4, fully coalesced ----
#pragma unroll
    for (int it = 0; it < QPB; ++it) {
        int p = it * BS + t;              // quad index within block [0,1280)
        int f = p / 40;                   // 40 quads per frame
        int off = (p - f * 40) * 4;
        float4 v = *(const float4*)(x + base + 4 * p);
        *(float4*)(&xs[f * SX + off]) = v;
    }
    __syncthreads();

    const int fi = t >> 3;       // frame within block [0,32)
    const int part = t & 7;      // n-range: [20*part, 20*part+20)
    const int sbase = SEG * part;

    // ---- window w[j] = x[sbase + j], j in [0,36), zero-padded past frame end ----
    float w[SEG + ORDER];
#pragma unroll
    for (int m = 0; m < (SEG + ORDER) / 4; ++m) {
        int idx = sbase + 4 * m;
        float4 v = make_float4(0.f, 0.f, 0.f, 0.f);
        if (idx < FRAME) v = *(const float4*)(&xs[fi * SX + idx]);
        w[4 * m + 0] = v.x; w[4 * m + 1] = v.y;
        w[4 * m + 2] = v.z; w[4 * m + 3] = v.w;
    }

    // ---- FIR look-back: pre[j] = x[sbase - 16 + j], zeros before frame start ----
    float pre[ORDER];
#pragma unroll
    for (int m = 0; m < ORDER / 4; ++m) {
        int idx = sbase - ORDER + 4 * m;
        float4 v = make_float4(0.f, 0.f, 0.f, 0.f);
        if (idx >= 0) v = *(const float4*)(&xs[fi * SX + idx]);
        pre[4 * m + 0] = v.x; pre[4 * m + 1] = v.y;
        pre[4 * m + 2] = v.z; pre[4 * m + 3] = v.w;
    }

    // ---- partial autocorrelation over 20 samples, all 17 lags ----
    float r[ORDER + 1];
#pragma unroll
    for (int k = 0; k <= ORDER; ++k) r[k] = 0.f;
#pragma unroll
    for (int n = 0; n < SEG; ++n) {
#pragma unroll
        for (int k = 0; k <= ORDER; ++k) {
            r[k] = fmaf(w[n], w[n + k], r[k]);
        }
    }
    // 8-lane butterfly: every lane of the group gets full-frame r[k]
#pragma unroll
    for (int k = 0; k <= ORDER; ++k) {
        r[k] += __shfl_xor(r[k], 1);
        r[k] += __shfl_xor(r[k], 2);
        r[k] += __shfl_xor(r[k], 4);
    }

    // ---- publish r[] once per frame (lane part==0) ----
    if (part == 0) {
#pragma unroll
        for (int m = 0; m < 4; ++m)
            *(float4*)(&rbuf[fi * AB + 4 * m]) =
                make_float4(r[4 * m], r[4 * m + 1], r[4 * m + 2], r[4 * m + 3]);
        rbuf[fi * AB + 16] = r[16];
    }
    __syncthreads();

    // ---- Levinson-Durbin: one thread per frame (wave 0 only) ----
    if (t < NF) {
        float rr[ORDER + 1];
#pragma unroll
        for (int m = 0; m < 4; ++m) {
            float4 v = *(const float4*)(&rbuf[t * AB + 4 * m]);
            rr[4 * m + 0] = v.x; rr[4 * m + 1] = v.y;
            rr[4 * m + 2] = v.z; rr[4 * m + 3] = v.w;
        }
        rr[16] = rbuf[t * AB + 16];

        float a[ORDER + 1];
        a[0] = 1.f;
#pragma unroll
        for (int j = 1; j <= ORDER; ++j) a[j] = 0.f;
        float e = (rr[0] != 0.f) ? rr[0] : LPC_EPS;  // e >= EPS > 0 afterwards
#pragma unroll
        for (int i = 1; i <= ORDER; ++i) {
            float acc = rr[i];
#pragma unroll
            for (int j = 1; j < i; ++j) acc -= a[j] * rr[i - j];
            // e >= EPS always; v_rcp_f32 (~1 ulp) vs IEEE divide: rel err ~1e-7
            float k = acc * __builtin_amdgcn_rcpf(e);
            // a_new[j] = a[j] - k*a[i-j] for j=1..i-1, done as (j, i-j) pairs:
#pragma unroll
            for (int j = 1; 2 * j < i; ++j) {
                float aj = a[j], aij = a[i - j];
                a[j]     = aj  - k * aij;
                a[i - j] = aij - k * aj;
            }
            if ((i & 1) == 0) {
                int m = i >> 1;                 // self-paired middle element
                a[m] = a[m] - k * a[m];
            }
            a[i] = k;
            e = fmaxf(e * (1.f - k * k), LPC_EPS);
        }
        // publish a[1..16] (a[0]==1 implicit)
#pragma unroll
        for (int m = 0; m < 4; ++m)
            *(float4*)(&abuf[t * AB + 4 * m]) =
                make_float4(a[4 * m + 1], a[4 * m + 2], a[4 * m + 3], a[4 * m + 4]);
    }
    __syncthreads();  // abuf visible; all xs reads already done before rbuf sync

    // ---- read back a[] (same address across the 8 lanes -> LDS broadcast) ----
    float a[ORDER + 1];
    a[0] = 1.f;
#pragma unroll
    for (int m = 0; m < 4; ++m) {
        float4 v = *(const float4*)(&abuf[fi * AB + 4 * m]);
        a[4 * m + 1] = v.x; a[4 * m + 2] = v.y;
        a[4 * m + 3] = v.z; a[4 * m + 4] = v.w;
    }

    // ---- FIR: res[sbase+n] = sum_k a[k] * x[sbase+n-k], written in place ----
#pragma unroll
    for (int m = 0; m < SEG / 4; ++m) {
        float o[4];
#pragma unroll
        for (int i = 0; i < 4; ++i) {
            int n = 4 * m + i;
            float s = 0.f;
#pragma unroll
            for (int k = 0; k <= ORDER; ++k) {
                int j = n - k;                       // compile-time
                float xv = (j >= 0) ? w[j] : pre[ORDER + j];
                s = fmaf(a[k], xv, s);
            }
            o[i] = s;
        }
        *(float4*)(&xs[fi * SX + sbase + 4 * m]) = make_float4(o[0], o[1], o[2], o[3]);
    }
    __syncthreads();

    // ---- stage out: fully coalesced, NON-TEMPORAL (output never re-read;
    //      nt keeps the write stream from evicting the input from L3) ----
#pragma unroll
    for (int it = 0; it < QPB; ++it) {
        int p = it * BS + t;
        int f = p / 40;
        int off = (p - f * 40) * 4;
        f4nt v = *(const f4nt*)(&xs[f * SX + off]);
        __builtin_nontemporal_store(v, (f4nt*)(out + base + 4 * p));
    }
}

extern "C" void kernel_launch(void* const* d_in, const int* in_sizes, int n_in,
                              void* d_out, int out_size, void* d_ws, size_t ws_size,
                              hipStream_t stream) {
    const float* x = (const float*)d_in[0];
    float* out = (float*)d_out;
    int total = in_sizes[0];                 // 20,480,000 = 128,000 frames
    int n_frames = total / FRAME;
    int n_blocks = n_frames / NF;            // 4000 (exact for this problem shape)
    lpc_fused<<<n_blocks, BS, 0, stream>>>(x, out);
}